// Round 1
// baseline (1351.625 us; speedup 1.0000x reference)
//
#include <hip/hip_runtime.h>
#include <cstdint>
#include <cstddef>

#define BS 64
#define SEQ 1024
#define IN_DIM 512
#define EMB 1024
#define HID 512
#define KSEL 306
#define MROWS (BS * KSEL)  // 19584

// ---------- meta: token_lens / eos per batch ----------
__global__ void k_meta(const int* __restrict__ text, int* __restrict__ lens,
                       int* __restrict__ eos) {
  int b = blockIdx.x;
  __shared__ int cnt;
  if (threadIdx.x == 0) cnt = 0;
  __syncthreads();
  int local = 0;
  for (int i = threadIdx.x; i < SEQ; i += blockDim.x)
    local += (text[b * SEQ + i] != 0) ? 1 : 0;
  atomicAdd(&cnt, local);
  __syncthreads();
  if (threadIdx.x == 0) {
    int L = cnt > 1 ? cnt : 1;
    lens[b] = L;
    int e = L - 1;
    if (e < 0) e = 0;
    if (e > SEQ - 1) e = SEQ - 1;
    eos[b] = e;
  }
}

// ---------- column softmax over rows, evaluated at eos row ----------
// atten_sel[b,c] = softmax_over_r(A[b,:,c])[eos] * mask, with column masking.
// Masked columns (c==0, c==eos, pad) are closed-form: 1/1024 or 0.
__global__ void k_softmax(const float* __restrict__ atten, const int* __restrict__ text,
                          const int* __restrict__ eos, float* __restrict__ selval) {
  int b = blockIdx.x >> 2;
  int c = ((blockIdx.x & 3) << 8) | threadIdx.x;
  int e = eos[b];
  const float* col = atten + ((size_t)b << 20) + c;
  float s = 0.f, v = 0.f;
  for (int r = 0; r < SEQ; ++r) {
    float x = col[(size_t)r << 10];
    if (!isfinite(x)) x = 0.f;  // nan_to_num(nan/±inf -> 0)
    if (r == e) v = x;
    s += __expf(x - 12.f);  // values are ~N(0,1): fixed shift, no overflow
  }
  int tok = text[(b << 10) | c];
  float res;
  if (tok == 0) res = 0.f;
  else if (c == 0 || c == e) res = 1.f / 1024.f;  // fully-masked column -> uniform
  else res = __expf(v - 12.f) / s;
  selval[(b << 10) | c] = res;
}

// ---------- top-K by rank counting (tie-break: lower index wins) ----------
__global__ void k_topk(const float* __restrict__ selval, int* __restrict__ selidx) {
  int b = blockIdx.x;
  __shared__ float vals[SEQ];
  for (int i = threadIdx.x; i < SEQ; i += blockDim.x)
    vals[i] = selval[(b << 10) + i];
  __syncthreads();
  for (int i = threadIdx.x; i < SEQ; i += blockDim.x) {
    float vc = vals[i];
    int rank = 0;
    for (int j = 0; j < SEQ; ++j) {
      float vj = vals[j];
      rank += (vj > vc || (vj == vc && j < i)) ? 1 : 0;
    }
    if (rank < KSEL) selidx[b * KSEL + rank] = i;
  }
}

// ---------- gather selected feature rows + L2 normalize ----------
__global__ void k_gather(const float* __restrict__ features, const int* __restrict__ sel,
                         float* __restrict__ xf) {
  int row = blockIdx.x;  // 0..MROWS-1
  int b = row / KSEL;
  int k = row - b * KSEL;
  int idx = sel[b * KSEL + k];
  const float4* src =
      (const float4*)(features + (((size_t)b << 10) + idx) * IN_DIM);
  float4 v = src[threadIdx.x];  // 128 threads * float4 = 512
  float ss = v.x * v.x + v.y * v.y + v.z * v.z + v.w * v.w;
#pragma unroll
  for (int off = 32; off > 0; off >>= 1) ss += __shfl_down(ss, off, 64);
  __shared__ float wsum[2];
  int lane = threadIdx.x & 63, wid = threadIdx.x >> 6;
  if (lane == 0) wsum[wid] = ss;
  __syncthreads();
  float total = wsum[0] + wsum[1];
  float norm = sqrtf(total);
  float scale = 1.f / fmaxf(norm, 1e-6f);
  v.x *= scale; v.y *= scale; v.z *= scale; v.w *= scale;
  ((float4*)xf)[(size_t)row * (IN_DIM / 4) + threadIdx.x] = v;
}

// ---------- generic fp32 tiled GEMM: C = A[MxK] * B[KxN] (+bias) (+=C) ----------
// 64x64 tile, 256 threads, 4x4 micro-tile, BK=16. M%64==0, N%64==0, K%16==0.
__global__ __launch_bounds__(256) void k_gemm(const float* __restrict__ A,
                                              const float* __restrict__ B,
                                              const float* __restrict__ bias,
                                              float* __restrict__ C, int M, int N,
                                              int K, int acc) {
  __shared__ float As[16][64];  // transposed: As[k][m]
  __shared__ float Bs[16][64];  // Bs[k][n]
  int tid = threadIdx.x;
  int m0 = blockIdx.x * 64, n0 = blockIdx.y * 64;
  int tx = tid & 15, ty = tid >> 4;
  int a_r = tid >> 2, a_c = (tid & 3) << 2;
  int b_r = tid >> 4, b_c = (tid & 15) << 2;
  float accu[4][4];
#pragma unroll
  for (int i = 0; i < 4; i++)
#pragma unroll
    for (int j = 0; j < 4; j++) accu[i][j] = 0.f;

  for (int k0 = 0; k0 < K; k0 += 16) {
    float4 av = *(const float4*)&A[(size_t)(m0 + a_r) * K + k0 + a_c];
    float4 bv = *(const float4*)&B[(size_t)(k0 + b_r) * N + n0 + b_c];
    As[a_c + 0][a_r] = av.x;
    As[a_c + 1][a_r] = av.y;
    As[a_c + 2][a_r] = av.z;
    As[a_c + 3][a_r] = av.w;
    *(float4*)&Bs[b_r][b_c] = bv;
    __syncthreads();
#pragma unroll
    for (int kk = 0; kk < 16; ++kk) {
      float4 a = *(const float4*)&As[kk][ty << 2];
      float4 b = *(const float4*)&Bs[kk][tx << 2];
      float aa[4] = {a.x, a.y, a.z, a.w};
      float bb[4] = {b.x, b.y, b.z, b.w};
#pragma unroll
      for (int i = 0; i < 4; i++)
#pragma unroll
        for (int j = 0; j < 4; j++) accu[i][j] = fmaf(aa[i], bb[j], accu[i][j]);
    }
    __syncthreads();
  }

#pragma unroll
  for (int i = 0; i < 4; i++) {
    int m = m0 + (ty << 2) + i;
    float* cp = &C[(size_t)m * N + n0 + (tx << 2)];
    float4 outv;
    outv.x = accu[i][0];
    outv.y = accu[i][1];
    outv.z = accu[i][2];
    outv.w = accu[i][3];
    if (bias) {
      const float* bp = &bias[n0 + (tx << 2)];
      outv.x += bp[0]; outv.y += bp[1]; outv.z += bp[2]; outv.w += bp[3];
    }
    if (acc) {
      float4 old = *(float4*)cp;
      outv.x += old.x; outv.y += old.y; outv.z += old.z; outv.w += old.w;
    }
    *(float4*)cp = outv;
  }
}

// ---------- BN stats: per-column sum & sumsq over MROWS rows ----------
__global__ void k_bnstats(const float* __restrict__ h, float* __restrict__ stats) {
  int r0 = blockIdx.x * 128;
  int c = threadIdx.x;  // 0..255 -> cols c and c+256
  float s0 = 0, q0 = 0, s1 = 0, q1 = 0;
  for (int r = 0; r < 128; ++r) {
    const float* row = h + (size_t)(r0 + r) * HID;
    float x0 = row[c], x1 = row[c + 256];
    s0 += x0; q0 += x0 * x0;
    s1 += x1; q1 += x1 * x1;
  }
  atomicAdd(&stats[c], s0);
  atomicAdd(&stats[HID + c], q0);
  atomicAdd(&stats[c + 256], s1);
  atomicAdd(&stats[HID + c + 256], q1);
}

__global__ void k_bnparam(const float* __restrict__ stats, const float* __restrict__ g,
                          const float* __restrict__ be, float* __restrict__ scsh) {
  int c = threadIdx.x;  // 512 threads
  float inv = 1.f / (float)MROWS;
  float mu = stats[c] * inv;
  float var = stats[HID + c] * inv - mu * mu;  // biased var
  var = fmaxf(var, 0.f);
  float sc = g[c] * rsqrtf(var + 1e-5f);
  scsh[c] = sc;
  scsh[HID + c] = fmaf(-mu, sc, be[c]);
}

__global__ void k_bnapply(float* __restrict__ h, const float* __restrict__ scsh) {
  size_t idx = (size_t)blockIdx.x * blockDim.x + threadIdx.x;
  size_t total = (size_t)MROWS * HID / 4;
  if (idx >= total) return;
  float4 x = ((float4*)h)[idx];
  int c = (int)(idx & 127) << 2;  // HID/4 = 128
  x.x = fmaxf(fmaf(x.x, scsh[c + 0], scsh[HID + c + 0]), 0.f);
  x.y = fmaxf(fmaf(x.y, scsh[c + 1], scsh[HID + c + 1]), 0.f);
  x.z = fmaxf(fmaf(x.z, scsh[c + 2], scsh[HID + c + 2]), 0.f);
  x.w = fmaxf(fmaf(x.w, scsh[c + 3], scsh[HID + c + 3]), 0.f);
  ((float4*)h)[idx] = x;
}

__global__ void k_biasc(const float* __restrict__ lin_b, const float* __restrict__ b2,
                        float* __restrict__ biasC) {
  int n = threadIdx.x;  // 1024 threads
  biasC[n] = lin_b[n] + b2[n];
}

// ---------- max-pool over K per (batch, emb) ----------
__global__ void k_maxpool(const float* __restrict__ fused, float* __restrict__ out) {
  int b = blockIdx.x;
  int c = (blockIdx.y << 8) | threadIdx.x;
  const float* p = fused + (((size_t)b * KSEL) << 10) + c;
  float m = -3.4e38f;
  for (int k = 0; k < KSEL; ++k) m = fmaxf(m, p[(size_t)k << 10]);
  out[(b << 10) | c] = m;
}

extern "C" void kernel_launch(void* const* d_in, const int* in_sizes, int n_in,
                              void* d_out, int out_size, void* d_ws, size_t ws_size,
                              hipStream_t stream) {
  const float* features = (const float*)d_in[0];
  const float* atten    = (const float*)d_in[1];
  const int*   text     = (const int*)d_in[2];
  const float* lin_w    = (const float*)d_in[3];
  const float* lin_b    = (const float*)d_in[4];
  const float* w1       = (const float*)d_in[5];
  const float* b1       = (const float*)d_in[6];
  const float* g1       = (const float*)d_in[7];
  const float* be1      = (const float*)d_in[8];
  const float* w2       = (const float*)d_in[9];
  const float* b2       = (const float*)d_in[10];
  float* out = (float*)d_out;

  char* ws = (char*)d_ws;
  int*   lens   = (int*)(ws + 0);
  int*   eos    = (int*)(ws + 256);
  float* stats  = (float*)(ws + 512);          // 1024 f32 (sum | sumsq)
  float* scsh   = (float*)(ws + 4608);         // 1024 f32 (scale | shift)
  float* biasC  = (float*)(ws + 8704);         // 1024 f32
  float* selval = (float*)(ws + 12800);        // 64*1024 f32
  int*   selidx = (int*)(ws + 274944);         // 64*306 int
  float* xf     = (float*)(ws + 353280);       // 19584*512 f32 (40 MB)
  float* h      = (float*)(ws + 40461312UL);   // 19584*512 f32 (40 MB)
  float* fused  = (float*)(ws + 80569344UL);   // 19584*1024 f32 (80 MB)
  // total ws usage: 160,785,408 bytes

  hipMemsetAsync(stats, 0, 1024 * sizeof(float), stream);

  k_meta<<<BS, 256, 0, stream>>>(text, lens, eos);
  k_softmax<<<BS * 4, 256, 0, stream>>>(atten, text, eos, selval);
  k_topk<<<BS, 256, 0, stream>>>(selval, selidx);
  k_gather<<<MROWS, 128, 0, stream>>>(features, selidx, xf);

  dim3 g1grid(MROWS / 64, HID / 64);
  k_gemm<<<g1grid, 256, 0, stream>>>(xf, w1, b1, h, MROWS, HID, IN_DIM, 0);

  k_bnstats<<<MROWS / 128, 256, 0, stream>>>(h, stats);
  k_bnparam<<<1, HID, 0, stream>>>(stats, g1, be1, scsh);
  k_bnapply<<<(MROWS * HID / 4 + 255) / 256, 256, 0, stream>>>(h, scsh);

  k_biasc<<<1, EMB, 0, stream>>>(lin_b, b2, biasC);
  dim3 g2grid(MROWS / 64, EMB / 64);
  k_gemm<<<g2grid, 256, 0, stream>>>(xf, lin_w, biasC, fused, MROWS, EMB, IN_DIM, 0);
  k_gemm<<<g2grid, 256, 0, stream>>>(h, w2, nullptr, fused, MROWS, EMB, IN_DIM, 1);

  k_maxpool<<<dim3(BS, 4), 256, 0, stream>>>(fused, out);
}

// Round 2
// 676.818 us; speedup vs baseline: 1.9970x; 1.9970x over previous
//
#include <hip/hip_runtime.h>
#include <cstdint>
#include <cstddef>

#define BS 64
#define SEQ 1024
#define IN_DIM 512
#define EMB 1024
#define HID 512
#define KSEL 306
#define MROWS (BS * KSEL)  // 19584 = 153 * 128

typedef __bf16 bf16_t;
typedef bf16_t bf16x8 __attribute__((ext_vector_type(8)));
typedef bf16_t bf16x4 __attribute__((ext_vector_type(4)));
typedef float f32x4 __attribute__((ext_vector_type(4)));

__device__ __forceinline__ void async16(const void* g, void* l) {
  __builtin_amdgcn_global_load_lds(
      (const __attribute__((address_space(1))) unsigned int*)g,
      (__attribute__((address_space(3))) unsigned int*)l, 16, 0, 0);
}

// ---------- meta: eos position per batch ----------
__global__ void k_meta(const int* __restrict__ text, int* __restrict__ eos) {
  int b = blockIdx.x;
  __shared__ int cnt;
  if (threadIdx.x == 0) cnt = 0;
  __syncthreads();
  int local = 0;
  for (int i = threadIdx.x; i < SEQ; i += blockDim.x)
    local += (text[b * SEQ + i] != 0) ? 1 : 0;
  atomicAdd(&cnt, local);
  __syncthreads();
  if (threadIdx.x == 0) {
    int L = cnt > 1 ? cnt : 1;
    int e = L - 1;
    if (e > SEQ - 1) e = SEQ - 1;
    eos[b] = e;
  }
}

// ---------- column exp-sum partials (softmax denominator) ----------
__global__ void k_colsum(const float* __restrict__ atten, float* __restrict__ colsum) {
  int b = blockIdx.x;
  int r0 = blockIdx.y << 7;
  int c = (blockIdx.z << 8) | threadIdx.x;
  const float* base = atten + ((size_t)b << 20) + ((size_t)r0 << 10) + c;
  float s = 0.f;
#pragma unroll 4
  for (int r = 0; r < 128; ++r) {
    float x = base[(size_t)r << 10];
    if (!isfinite(x)) x = 0.f;  // nan_to_num
    s += __expf(x - 12.f);      // values ~N(0,1): fixed shift, no overflow
  }
  atomicAdd(&colsum[(b << 10) | c], s);
}

// ---------- selected (eos-row) softmax value per column, with masking ----------
__global__ void k_selval(const float* __restrict__ atten, const int* __restrict__ text,
                         const int* __restrict__ eos, const float* __restrict__ colsum,
                         float* __restrict__ selval) {
  int b = blockIdx.x >> 2;
  int c = ((blockIdx.x & 3) << 8) | threadIdx.x;
  int e = eos[b];
  float v = atten[((size_t)b << 20) + ((size_t)e << 10) + c];
  if (!isfinite(v)) v = 0.f;
  int tok = text[(b << 10) | c];
  float res;
  if (tok == 0) res = 0.f;
  else if (c == 0 || c == e) res = 1.f / 1024.f;  // fully-masked column -> uniform
  else res = __expf(v - 12.f) / colsum[(b << 10) | c];
  selval[(b << 10) | c] = res;
}

// ---------- top-K by rank counting (tie-break: lower index wins) ----------
__global__ void k_topk(const float* __restrict__ selval, int* __restrict__ selidx) {
  int b = blockIdx.x;
  __shared__ float vals[SEQ];
  int i = threadIdx.x;
  vals[i] = selval[(b << 10) + i];
  __syncthreads();
  float vc = vals[i];
  int rank = 0;
  for (int j = 0; j < SEQ; ++j) {
    float vj = vals[j];
    rank += (vj > vc || (vj == vc && j < i)) ? 1 : 0;
  }
  if (rank < KSEL) selidx[b * KSEL + rank] = i;
}

// ---------- gather selected rows + L2 normalize -> bf16 into xcat[:, 0:512] ----------
__global__ void k_gather(const float* __restrict__ features, const int* __restrict__ sel,
                         bf16_t* __restrict__ xcat) {
  int row = blockIdx.x;  // 0..MROWS-1
  int b = row / KSEL;
  int k = row - b * KSEL;
  int idx = sel[b * KSEL + k];
  const float4* src = (const float4*)(features + (((size_t)b << 10) + idx) * IN_DIM);
  float4 v = src[threadIdx.x];  // 128 threads * float4 = 512
  float ss = v.x * v.x + v.y * v.y + v.z * v.z + v.w * v.w;
#pragma unroll
  for (int off = 32; off > 0; off >>= 1) ss += __shfl_down(ss, off, 64);
  __shared__ float wsum[2];
  int lane = threadIdx.x & 63, wid = threadIdx.x >> 6;
  if (lane == 0) wsum[wid] = ss;
  __syncthreads();
  float total = wsum[0] + wsum[1];
  float scale = 1.f / fmaxf(sqrtf(total), 1e-6f);
  bf16x4 o;
  o[0] = (bf16_t)(v.x * scale);
  o[1] = (bf16_t)(v.y * scale);
  o[2] = (bf16_t)(v.z * scale);
  o[3] = (bf16_t)(v.w * scale);
  *(bf16x4*)(xcat + (size_t)row * EMB + (threadIdx.x << 2)) = o;
}

// ---------- tiled transpose + f32->bf16: dst[n][k] = src[k][n] ----------
__global__ void k_transpose_bf16(const float* __restrict__ src, int srcld,
                                 bf16_t* __restrict__ dst, int dstld) {
  __shared__ float tile[32][33];
  int k0 = blockIdx.x << 5, n0 = blockIdx.y << 5;
  int tx = threadIdx.x, ty = threadIdx.y;
#pragma unroll
  for (int i = 0; i < 4; i++)
    tile[ty + 8 * i][tx] = src[(size_t)(k0 + ty + 8 * i) * srcld + n0 + tx];
  __syncthreads();
#pragma unroll
  for (int i = 0; i < 4; i++)
    dst[(size_t)(n0 + ty + 8 * i) * dstld + k0 + tx] = (bf16_t)tile[tx][ty + 8 * i];
}

__global__ void k_biasc(const float* __restrict__ lin_b, const float* __restrict__ b2,
                        float* __restrict__ biasC) {
  int n = threadIdx.x;
  biasC[n] = lin_b[n] + b2[n];
}

// ---------- bf16 MFMA GEMM: C[M x N] = A[M x K](lda) * Bt[N x K](ldb)^T + bias ----------
// 128x128 tile, 256 threads = 4 waves, each wave 4x4 of 16x16x32 MFMA. K % 32 == 0.
__global__ __launch_bounds__(256, 2) void k_mfma_gemm(
    const bf16_t* __restrict__ A, int lda, const bf16_t* __restrict__ Bt, int ldb,
    const float* __restrict__ bias, float* __restrict__ C, int ldc, int K) {
  __shared__ __align__(16) bf16_t As[128 * 32];
  __shared__ __align__(16) bf16_t Bs[128 * 32];
  int tid = threadIdx.x;
  int m0 = blockIdx.x << 7, n0 = blockIdx.y << 7;
  int wave = tid >> 6, lane = tid & 63;
  int wm = (wave >> 1) << 6, wn = (wave & 1) << 6;
  int lrow = lane & 15, quad = lane >> 4;

  f32x4 acc[4][4];
#pragma unroll
  for (int i = 0; i < 4; i++)
#pragma unroll
    for (int j = 0; j < 4; j++) acc[i][j] = (f32x4){0.f, 0.f, 0.f, 0.f};

  // staging: chunk c covers 16B; row = c>>2, kcol = (c&3)*8
  int c0 = tid, c1 = 256 + tid;
  int ar0 = c0 >> 2, ak0 = (c0 & 3) << 3;
  int ar1 = c1 >> 2, ak1 = (c1 & 3) << 3;
  const bf16_t* Ap0 = A + (size_t)(m0 + ar0) * lda + ak0;
  const bf16_t* Ap1 = A + (size_t)(m0 + ar1) * lda + ak1;
  const bf16_t* Bp0 = Bt + (size_t)(n0 + ar0) * ldb + ak0;
  const bf16_t* Bp1 = Bt + (size_t)(n0 + ar1) * ldb + ak1;

  for (int k0 = 0; k0 < K; k0 += 32) {
    async16(Ap0 + k0, &As[c0 << 3]);
    async16(Ap1 + k0, &As[c1 << 3]);
    async16(Bp0 + k0, &Bs[c0 << 3]);
    async16(Bp1 + k0, &Bs[c1 << 3]);
    __syncthreads();  // drains vmcnt (global_load_lds) + lgkm

    bf16x8 af[4], bfr[4];
#pragma unroll
    for (int i = 0; i < 4; i++)
      af[i] = *(const bf16x8*)&As[((wm + (i << 4) + lrow) << 5) + (quad << 3)];
#pragma unroll
    for (int j = 0; j < 4; j++)
      bfr[j] = *(const bf16x8*)&Bs[((wn + (j << 4) + lrow) << 5) + (quad << 3)];
#pragma unroll
    for (int i = 0; i < 4; i++)
#pragma unroll
      for (int j = 0; j < 4; j++)
        acc[i][j] = __builtin_amdgcn_mfma_f32_16x16x32_bf16(af[i], bfr[j], acc[i][j], 0, 0, 0);
    __syncthreads();
  }

  // C/D layout: col = lane&15, row = quad*4 + reg
#pragma unroll
  for (int j = 0; j < 4; j++) {
    int n = n0 + wn + (j << 4) + lrow;
    float bv = bias ? bias[n] : 0.f;
#pragma unroll
    for (int i = 0; i < 4; i++) {
      int mbase = m0 + wm + (i << 4) + (quad << 2);
#pragma unroll
      for (int r = 0; r < 4; r++)
        C[(size_t)(mbase + r) * ldc + n] = acc[i][j][r] + bv;
    }
  }
}

// ---------- BN stats: per-column sum & sumsq over MROWS rows ----------
__global__ void k_bnstats(const float* __restrict__ h, float* __restrict__ stats) {
  int r0 = blockIdx.x << 7;
  int c = threadIdx.x;  // cols c and c+256
  float s0 = 0, q0 = 0, s1 = 0, q1 = 0;
  for (int r = 0; r < 128; ++r) {
    const float* row = h + (size_t)(r0 + r) * HID;
    float x0 = row[c], x1 = row[c + 256];
    s0 += x0; q0 += x0 * x0;
    s1 += x1; q1 += x1 * x1;
  }
  atomicAdd(&stats[c], s0);
  atomicAdd(&stats[HID + c], q0);
  atomicAdd(&stats[c + 256], s1);
  atomicAdd(&stats[HID + c + 256], q1);
}

__global__ void k_bnparam(const float* __restrict__ stats, const float* __restrict__ g,
                          const float* __restrict__ be, float* __restrict__ scsh) {
  int c = threadIdx.x;  // 512 threads
  float inv = 1.f / (float)MROWS;
  float mu = stats[c] * inv;
  float var = stats[HID + c] * inv - mu * mu;  // biased var
  var = fmaxf(var, 0.f);
  float sc = g[c] * rsqrtf(var + 1e-5f);
  scsh[c] = sc;
  scsh[HID + c] = fmaf(-mu, sc, be[c]);
}

// BN apply + ReLU, emit bf16 into xcat[:, 512:1024]
__global__ void k_bnapply(const float* __restrict__ h, const float* __restrict__ scsh,
                          bf16_t* __restrict__ xcat) {
  size_t idx = (size_t)blockIdx.x * blockDim.x + threadIdx.x;  // over MROWS*128
  float4 x = ((const float4*)h)[idx];
  int c = (int)(idx & 127) << 2;
  size_t row = idx >> 7;
  float a0 = fmaxf(fmaf(x.x, scsh[c + 0], scsh[HID + c + 0]), 0.f);
  float a1 = fmaxf(fmaf(x.y, scsh[c + 1], scsh[HID + c + 1]), 0.f);
  float a2 = fmaxf(fmaf(x.z, scsh[c + 2], scsh[HID + c + 2]), 0.f);
  float a3 = fmaxf(fmaf(x.w, scsh[c + 3], scsh[HID + c + 3]), 0.f);
  bf16x4 o;
  o[0] = (bf16_t)a0; o[1] = (bf16_t)a1; o[2] = (bf16_t)a2; o[3] = (bf16_t)a3;
  *(bf16x4*)(xcat + row * EMB + 512 + c) = o;
}

// ---------- max-pool over K per (batch, emb) ----------
__global__ void k_maxpool(const float* __restrict__ fused, float* __restrict__ out) {
  int b = blockIdx.x;
  int c = (blockIdx.y << 8) | threadIdx.x;
  const float* p = fused + (((size_t)b * KSEL) << 10) + c;
  float m = -3.4e38f;
  for (int k = 0; k < KSEL; ++k) m = fmaxf(m, p[(size_t)k << 10]);
  out[(b << 10) | c] = m;
}

extern "C" void kernel_launch(void* const* d_in, const int* in_sizes, int n_in,
                              void* d_out, int out_size, void* d_ws, size_t ws_size,
                              hipStream_t stream) {
  const float* features = (const float*)d_in[0];
  const float* atten    = (const float*)d_in[1];
  const int*   text     = (const int*)d_in[2];
  const float* lin_w    = (const float*)d_in[3];
  const float* lin_b    = (const float*)d_in[4];
  const float* w1       = (const float*)d_in[5];
  const float* b1       = (const float*)d_in[6];
  const float* g1       = (const float*)d_in[7];
  const float* be1      = (const float*)d_in[8];
  const float* w2       = (const float*)d_in[9];
  const float* b2       = (const float*)d_in[10];
  float* out = (float*)d_out;

  char* ws = (char*)d_ws;
  int*    eos    = (int*)(ws + 0);               // 64 int
  float*  stats  = (float*)(ws + 256);           // 1024 f32
  float*  scsh   = (float*)(ws + 4608);          // 1024 f32
  float*  biasC  = (float*)(ws + 8704);          // 1024 f32
  float*  colsum = (float*)(ws + 12800);         // 64*1024 f32
  float*  selval = (float*)(ws + 274944);        // 64*1024 f32
  int*    selidx = (int*)(ws + 537088);          // 64*306 int
  bf16_t* w1t    = (bf16_t*)(ws + 615424);       // 512*512 bf16
  bf16_t* wcatt  = (bf16_t*)(ws + 1139712);      // 1024*1024 bf16
  bf16_t* xcat   = (bf16_t*)(ws + 3236864);      // 19584*1024 bf16
  float*  h      = (float*)(ws + 43344896UL);    // 19584*512 f32
  float*  fused  = (float*)(ws + 83452928UL);    // 19584*1024 f32
  // total: 163,668,992 bytes

  hipMemsetAsync(stats, 0, 4096, stream);
  hipMemsetAsync(colsum, 0, 64 * 1024 * sizeof(float), stream);

  k_meta<<<BS, 256, 0, stream>>>(text, eos);
  k_colsum<<<dim3(BS, 8, 4), 256, 0, stream>>>(atten, colsum);
  k_selval<<<BS * 4, 256, 0, stream>>>(atten, text, eos, colsum, selval);
  k_topk<<<BS, 1024, 0, stream>>>(selval, selidx);
  k_gather<<<MROWS, 128, 0, stream>>>(features, selidx, xcat);

  // weight prep (runs every call; tiny)
  k_transpose_bf16<<<dim3(16, 16), dim3(32, 8), 0, stream>>>(w1, HID, w1t, IN_DIM);
  k_transpose_bf16<<<dim3(16, 32), dim3(32, 8), 0, stream>>>(lin_w, EMB, wcatt, EMB);
  k_transpose_bf16<<<dim3(16, 32), dim3(32, 8), 0, stream>>>(w2, EMB, wcatt + 512, EMB);
  k_biasc<<<1, EMB, 0, stream>>>(lin_b, b2, biasC);

  // GEMM1: h = xcat[:, :512] @ w1 + b1   (M=19584, N=512, K=512)
  k_mfma_gemm<<<dim3(MROWS / 128, HID / 128), 256, 0, stream>>>(
      xcat, EMB, w1t, IN_DIM, b1, h, HID, IN_DIM);

  k_bnstats<<<MROWS / 128, 256, 0, stream>>>(h, stats);
  k_bnparam<<<1, HID, 0, stream>>>(stats, g1, be1, scsh);
  k_bnapply<<<(MROWS * (HID / 4)) / 256, 256, 0, stream>>>(h, scsh, xcat);

  // GEMM2: fused = [xf | relu(bn(h))] @ [lin_w ; w2] + (lin_b + b2)
  // (M=19584, N=1024, K=1024)
  k_mfma_gemm<<<dim3(MROWS / 128, EMB / 128), 256, 0, stream>>>(
      xcat, EMB, wcatt, EMB, biasC, fused, EMB, EMB);

  k_maxpool<<<dim3(BS, 4), 256, 0, stream>>>(fused, out);
}

// Round 3
// 612.511 us; speedup vs baseline: 2.2067x; 1.1050x over previous
//
#include <hip/hip_runtime.h>
#include <cstdint>
#include <cstddef>
#include <cmath>

#define BS 64
#define SEQ 1024
#define IN_DIM 512
#define EMB 1024
#define HID 512
#define KSEL 306
#define MROWS (BS * KSEL)  // 19584 = 153 * 128

typedef __bf16 bf16_t;
typedef bf16_t bf16x8 __attribute__((ext_vector_type(8)));
typedef bf16_t bf16x4 __attribute__((ext_vector_type(4)));
typedef float f32x4 __attribute__((ext_vector_type(4)));

__device__ __forceinline__ void async16(const void* g, void* l) {
  __builtin_amdgcn_global_load_lds(
      (const __attribute__((address_space(1))) unsigned int*)g,
      (__attribute__((address_space(3))) unsigned int*)l, 16, 0, 0);
}

// float atomic max via signed-max / unsigned-min trick (no NaNs present).
__device__ __forceinline__ void atomicMaxF(float* a, float v) {
  if (v >= 0.f)
    atomicMax((int*)a, __float_as_int(v));
  else
    atomicMin((unsigned int*)a, __float_as_uint(v));
}

// ---------- meta: eos position per batch; init out to -inf ----------
__global__ void k_meta(const int* __restrict__ text, int* __restrict__ eos,
                       float* __restrict__ out) {
  int b = blockIdx.x;
  __shared__ int cnt;
  if (threadIdx.x == 0) cnt = 0;
  __syncthreads();
  int local = 0;
  for (int i = threadIdx.x; i < SEQ; i += blockDim.x)
    local += (text[b * SEQ + i] != 0) ? 1 : 0;
  atomicAdd(&cnt, local);
  for (int c = threadIdx.x; c < EMB; c += blockDim.x)
    out[(b << 10) + c] = -INFINITY;
  __syncthreads();
  if (threadIdx.x == 0) {
    int L = cnt > 1 ? cnt : 1;
    int e = L - 1;
    if (e > SEQ - 1) e = SEQ - 1;
    eos[b] = e;
  }
}

// ---------- column exp-sum partials (softmax denominator), no atomics ----------
// grid (BS, 16); thread covers 4 adjacent columns, wave covers a full row (4KB).
__global__ void k_colsum(const float* __restrict__ atten, float* __restrict__ part) {
  int b = blockIdx.x;
  int r0 = blockIdx.y << 6;
  int c = threadIdx.x << 2;
  const float* base = atten + ((size_t)b << 20) + ((size_t)r0 << 10) + c;
  float4 s = {0.f, 0.f, 0.f, 0.f};
#pragma unroll 4
  for (int r = 0; r < 64; ++r) {
    float4 x = *(const float4*)(base + ((size_t)r << 10));
    s.x += __expf((isfinite(x.x) ? x.x : 0.f) - 12.f);
    s.y += __expf((isfinite(x.y) ? x.y : 0.f) - 12.f);
    s.z += __expf((isfinite(x.z) ? x.z : 0.f) - 12.f);
    s.w += __expf((isfinite(x.w) ? x.w : 0.f) - 12.f);
  }
  *(float4*)&part[((((size_t)blockIdx.y << 6) | b) << 10) | c] = s;
}

// ---------- selected (eos-row) softmax value per column, with masking ----------
__global__ void k_selval(const float* __restrict__ atten, const int* __restrict__ text,
                         const int* __restrict__ eos, const float* __restrict__ part,
                         float* __restrict__ selval) {
  int b = blockIdx.x >> 2;
  int c = ((blockIdx.x & 3) << 8) | threadIdx.x;
  int e = eos[b];
  float cs = 0.f;
#pragma unroll
  for (int p = 0; p < 16; ++p) cs += part[(((p << 6) | b) << 10) | c];
  float v = atten[((size_t)b << 20) + ((size_t)e << 10) + c];
  if (!isfinite(v)) v = 0.f;
  int tok = text[(b << 10) | c];
  float res;
  if (tok == 0) res = 0.f;
  else if (c == 0 || c == e) res = 1.f / 1024.f;  // fully-masked column -> uniform
  else res = __expf(v - 12.f) / cs;
  selval[(b << 10) | c] = res;
}

// ---------- top-K by rank counting (tie-break: lower index wins) ----------
__global__ void k_topk(const float* __restrict__ selval, int* __restrict__ selidx) {
  int b = blockIdx.x;
  __shared__ float vals[SEQ];
  int i = threadIdx.x;
  vals[i] = selval[(b << 10) + i];
  __syncthreads();
  float vc = vals[i];
  int rank = 0;
  for (int j = 0; j < SEQ; ++j) {
    float vj = vals[j];
    rank += (vj > vc || (vj == vc && j < i)) ? 1 : 0;
  }
  if (rank < KSEL) selidx[b * KSEL + rank] = i;
}

// ---------- gather selected rows + L2 normalize -> bf16 into xcat[:, 0:512] ----------
__global__ void k_gather(const float* __restrict__ features, const int* __restrict__ sel,
                         bf16_t* __restrict__ xcat) {
  int row = blockIdx.x;  // 0..MROWS-1
  int b = row / KSEL;
  int k = row - b * KSEL;
  int idx = sel[b * KSEL + k];
  const float4* src = (const float4*)(features + (((size_t)b << 10) + idx) * IN_DIM);
  float4 v = src[threadIdx.x];  // 128 threads * float4 = 512
  float ss = v.x * v.x + v.y * v.y + v.z * v.z + v.w * v.w;
#pragma unroll
  for (int off = 32; off > 0; off >>= 1) ss += __shfl_down(ss, off, 64);
  __shared__ float wsum[2];
  int lane = threadIdx.x & 63, wid = threadIdx.x >> 6;
  if (lane == 0) wsum[wid] = ss;
  __syncthreads();
  float total = wsum[0] + wsum[1];
  float scale = 1.f / fmaxf(sqrtf(total), 1e-6f);
  bf16x4 o;
  o[0] = (bf16_t)(v.x * scale);
  o[1] = (bf16_t)(v.y * scale);
  o[2] = (bf16_t)(v.z * scale);
  o[3] = (bf16_t)(v.w * scale);
  *(bf16x4*)(xcat + (size_t)row * EMB + (threadIdx.x << 2)) = o;
}

// ---------- tiled transpose + f32->bf16: dst[n][k] = src[k][n] ----------
__global__ void k_transpose_bf16(const float* __restrict__ src, int srcld,
                                 bf16_t* __restrict__ dst, int dstld) {
  __shared__ float tile[32][33];
  int k0 = blockIdx.x << 5, n0 = blockIdx.y << 5;
  int tx = threadIdx.x, ty = threadIdx.y;
#pragma unroll
  for (int i = 0; i < 4; i++)
    tile[ty + 8 * i][tx] = src[(size_t)(k0 + ty + 8 * i) * srcld + n0 + tx];
  __syncthreads();
#pragma unroll
  for (int i = 0; i < 4; i++)
    dst[(size_t)(n0 + ty + 8 * i) * dstld + k0 + tx] = (bf16_t)tile[tx][ty + 8 * i];
}

__global__ void k_biasc(const float* __restrict__ lin_b, const float* __restrict__ b2,
                        float* __restrict__ biasC) {
  int n = threadIdx.x;
  biasC[n] = lin_b[n] + b2[n];
}

// ---------- bf16 MFMA GEMM: 128x128 tile, 4 waves, 16x16x32 MFMA ----------
// MODE 0: C = A*Bt^T + bias, plus BN column sum/sumsq atomics into stats.
// MODE 1: no C write; v = A*Bt^T + bias; per-batch column max atomics into outmax.
template <int MODE>
__global__ __launch_bounds__(256, 2) void k_mfma_gemm(
    const bf16_t* __restrict__ A, int lda, const bf16_t* __restrict__ Bt, int ldb,
    const float* __restrict__ bias, float* __restrict__ C, int ldc, int K,
    float* __restrict__ stats, float* __restrict__ outmax) {
  __shared__ __align__(16) bf16_t As[128 * 32];
  __shared__ __align__(16) bf16_t Bs[128 * 32];
  int tid = threadIdx.x;
  int m0 = blockIdx.x << 7, n0 = blockIdx.y << 7;
  int wave = tid >> 6, lane = tid & 63;
  int wm = (wave >> 1) << 6, wn = (wave & 1) << 6;
  int lrow = lane & 15, quad = lane >> 4;

  f32x4 acc[4][4];
#pragma unroll
  for (int i = 0; i < 4; i++)
#pragma unroll
    for (int j = 0; j < 4; j++) acc[i][j] = (f32x4){0.f, 0.f, 0.f, 0.f};

  // staging: chunk c covers 16B; row = c>>2, kcol = (c&3)*8
  int c0 = tid, c1 = 256 + tid;
  int ar0 = c0 >> 2, ak0 = (c0 & 3) << 3;
  int ar1 = c1 >> 2, ak1 = (c1 & 3) << 3;
  const bf16_t* Ap0 = A + (size_t)(m0 + ar0) * lda + ak0;
  const bf16_t* Ap1 = A + (size_t)(m0 + ar1) * lda + ak1;
  const bf16_t* Bp0 = Bt + (size_t)(n0 + ar0) * ldb + ak0;
  const bf16_t* Bp1 = Bt + (size_t)(n0 + ar1) * ldb + ak1;

  for (int k0 = 0; k0 < K; k0 += 32) {
    async16(Ap0 + k0, &As[c0 << 3]);
    async16(Ap1 + k0, &As[c1 << 3]);
    async16(Bp0 + k0, &Bs[c0 << 3]);
    async16(Bp1 + k0, &Bs[c1 << 3]);
    __syncthreads();

    bf16x8 af[4], bfr[4];
#pragma unroll
    for (int i = 0; i < 4; i++)
      af[i] = *(const bf16x8*)&As[((wm + (i << 4) + lrow) << 5) + (quad << 3)];
#pragma unroll
    for (int j = 0; j < 4; j++)
      bfr[j] = *(const bf16x8*)&Bs[((wn + (j << 4) + lrow) << 5) + (quad << 3)];
#pragma unroll
    for (int i = 0; i < 4; i++)
#pragma unroll
      for (int j = 0; j < 4; j++)
        acc[i][j] = __builtin_amdgcn_mfma_f32_16x16x32_bf16(af[i], bfr[j], acc[i][j], 0, 0, 0);
    __syncthreads();
  }

  // C/D layout: col = lane&15, row = quad*4 + reg
  if (MODE == 0) {
#pragma unroll
    for (int j = 0; j < 4; j++) {
      int n = n0 + wn + (j << 4) + lrow;
      float bv = bias[n];
      float s = 0.f, q = 0.f;
#pragma unroll
      for (int i = 0; i < 4; i++) {
        int mbase = m0 + wm + (i << 4) + (quad << 2);
#pragma unroll
        for (int r = 0; r < 4; r++) {
          float v = acc[i][j][r] + bv;
          C[(size_t)(mbase + r) * ldc + n] = v;
          s += v;
          q += v * v;
        }
      }
      s += __shfl_xor(s, 16, 64);
      s += __shfl_xor(s, 32, 64);
      q += __shfl_xor(q, 16, 64);
      q += __shfl_xor(q, 32, 64);
      if (quad == 0) {
        atomicAdd(&stats[n], s);
        atomicAdd(&stats[HID + n], q);
      }
    }
  } else {
    int mw = m0 + wm;          // wave covers rows mw .. mw+63
    int b0w = mw / KSEL;       // tile spans <= 2 batches (64 < 306)
    int cut = (b0w + 1) * KSEL;
#pragma unroll
    for (int j = 0; j < 4; j++) {
      int n = n0 + wn + (j << 4) + lrow;
      float bv = bias[n];
      float mx0 = -INFINITY, mx1 = -INFINITY;
#pragma unroll
      for (int i = 0; i < 4; i++) {
#pragma unroll
        for (int r = 0; r < 4; r++) {
          int m = mw + (i << 4) + (quad << 2) + r;
          float v = acc[i][j][r] + bv;
          if (m < cut) mx0 = fmaxf(mx0, v);
          else mx1 = fmaxf(mx1, v);
        }
      }
      mx0 = fmaxf(mx0, __shfl_xor(mx0, 16, 64));
      mx0 = fmaxf(mx0, __shfl_xor(mx0, 32, 64));
      mx1 = fmaxf(mx1, __shfl_xor(mx1, 16, 64));
      mx1 = fmaxf(mx1, __shfl_xor(mx1, 32, 64));
      if (quad == 0) {
        atomicMaxF(&outmax[(b0w << 10) + n], mx0);
        if (cut < mw + 64) atomicMaxF(&outmax[((b0w + 1) << 10) + n], mx1);
      }
    }
  }
}

__global__ void k_bnparam(const float* __restrict__ stats, const float* __restrict__ g,
                          const float* __restrict__ be, float* __restrict__ scsh) {
  int c = threadIdx.x;  // 512 threads
  float inv = 1.f / (float)MROWS;
  float mu = stats[c] * inv;
  float var = stats[HID + c] * inv - mu * mu;  // biased var
  var = fmaxf(var, 0.f);
  float sc = g[c] * rsqrtf(var + 1e-5f);
  scsh[c] = sc;
  scsh[HID + c] = fmaf(-mu, sc, be[c]);
}

// BN apply + ReLU, emit bf16 into xcat[:, 512:1024]
__global__ void k_bnapply(const float* __restrict__ h, const float* __restrict__ scsh,
                          bf16_t* __restrict__ xcat) {
  size_t idx = (size_t)blockIdx.x * blockDim.x + threadIdx.x;  // over MROWS*128
  float4 x = ((const float4*)h)[idx];
  int c = (int)(idx & 127) << 2;
  size_t row = idx >> 7;
  float a0 = fmaxf(fmaf(x.x, scsh[c + 0], scsh[HID + c + 0]), 0.f);
  float a1 = fmaxf(fmaf(x.y, scsh[c + 1], scsh[HID + c + 1]), 0.f);
  float a2 = fmaxf(fmaf(x.z, scsh[c + 2], scsh[HID + c + 2]), 0.f);
  float a3 = fmaxf(fmaf(x.w, scsh[c + 3], scsh[HID + c + 3]), 0.f);
  bf16x4 o;
  o[0] = (bf16_t)a0; o[1] = (bf16_t)a1; o[2] = (bf16_t)a2; o[3] = (bf16_t)a3;
  *(bf16x4*)(xcat + row * EMB + 512 + c) = o;
}

extern "C" void kernel_launch(void* const* d_in, const int* in_sizes, int n_in,
                              void* d_out, int out_size, void* d_ws, size_t ws_size,
                              hipStream_t stream) {
  const float* features = (const float*)d_in[0];
  const float* atten    = (const float*)d_in[1];
  const int*   text     = (const int*)d_in[2];
  const float* lin_w    = (const float*)d_in[3];
  const float* lin_b    = (const float*)d_in[4];
  const float* w1       = (const float*)d_in[5];
  const float* b1       = (const float*)d_in[6];
  const float* g1       = (const float*)d_in[7];
  const float* be1      = (const float*)d_in[8];
  const float* w2       = (const float*)d_in[9];
  const float* b2       = (const float*)d_in[10];
  float* out = (float*)d_out;

  char* ws = (char*)d_ws;
  int*    eos    = (int*)(ws + 0);               // 64 int
  float*  stats  = (float*)(ws + 256);           // 1024 f32
  float*  scsh   = (float*)(ws + 4608);          // 1024 f32
  float*  biasC  = (float*)(ws + 8704);          // 1024 f32
  float*  part   = (float*)(ws + 12800);         // 16*64*1024 f32 (4 MB)
  float*  selval = (float*)(ws + 4207104UL);     // 64*1024 f32
  int*    selidx = (int*)(ws + 4469248UL);       // 64*306 int
  bf16_t* w1t    = (bf16_t*)(ws + 4547584UL);    // 512*512 bf16
  bf16_t* wcatt  = (bf16_t*)(ws + 5071872UL);    // 1024*1024 bf16
  bf16_t* xcat   = (bf16_t*)(ws + 7169024UL);    // 19584*1024 bf16 (40 MB)
  float*  h      = (float*)(ws + 47277056UL);    // 19584*512 f32 (40 MB)
  // total: 87,385,088 bytes

  hipMemsetAsync(stats, 0, 4096, stream);

  k_meta<<<BS, 256, 0, stream>>>(text, eos, out);
  k_colsum<<<dim3(BS, 16), 256, 0, stream>>>(atten, part);
  k_selval<<<BS * 4, 256, 0, stream>>>(atten, text, eos, part, selval);
  k_topk<<<BS, 1024, 0, stream>>>(selval, selidx);
  k_gather<<<MROWS, 128, 0, stream>>>(features, selidx, xcat);

  // weight prep (runs every call; tiny)
  k_transpose_bf16<<<dim3(16, 16), dim3(32, 8), 0, stream>>>(w1, HID, w1t, IN_DIM);
  k_transpose_bf16<<<dim3(16, 32), dim3(32, 8), 0, stream>>>(lin_w, EMB, wcatt, EMB);
  k_transpose_bf16<<<dim3(16, 32), dim3(32, 8), 0, stream>>>(w2, EMB, wcatt + 512, EMB);
  k_biasc<<<1, EMB, 0, stream>>>(lin_b, b2, biasC);

  // GEMM1: h = xcat[:, :512] @ w1 + b1, fused BN stats (M=19584, N=512, K=512)
  k_mfma_gemm<0><<<dim3(MROWS / 128, HID / 128), 256, 0, stream>>>(
      xcat, EMB, w1t, IN_DIM, b1, h, HID, IN_DIM, stats, nullptr);

  k_bnparam<<<1, HID, 0, stream>>>(stats, g1, be1, scsh);
  k_bnapply<<<(MROWS * (HID / 4)) / 256, 256, 0, stream>>>(h, scsh, xcat);

  // GEMM2: fused = [xf | relu(bn(h))] @ [lin_w ; w2] + (lin_b+b2), fused max-pool
  // (M=19584, N=1024, K=1024); no C materialization.
  k_mfma_gemm<1><<<dim3(MROWS / 128, EMB / 128), 256, 0, stream>>>(
      xcat, EMB, wcatt, EMB, biasC, nullptr, 0, EMB, nullptr, out);
}